// Round 6
// baseline (92.634 us; speedup 1.0000x reference)
//
#include <hip/hip_runtime.h>
#include <math.h>

#define DIM 256
typedef float v2f  __attribute__((ext_vector_type(2)));
typedef _Float16 f16x8 __attribute__((ext_vector_type(8)));
typedef float f32x4 __attribute__((ext_vector_type(4)));

__device__ __forceinline__ v2f mk2(float a, float b) { v2f r; r.x = a; r.y = b; return r; }
__device__ __forceinline__ float rl(float v, int l) {
    return __uint_as_float(__builtin_amdgcn_readlane(__float_as_uint(v), l));
}

// RY on v2f-index bit B2 (amp bit B2+1) of a 16-entry array.
template<int B2>
__device__ __forceinline__ void ry_pk(v2f* v, float c, float s) {
#pragma unroll
    for (int p = 0; p < 16; ++p)
        if (!(p & (1 << B2))) {
            const int q = p | (1 << B2);
            v2f lo = v[p], hi = v[q];
            v[p] = c * lo - s * hi;
            v[q] = s * lo + c * hi;
        }
}
__device__ __forceinline__ void ry_intra(v2f* v, float c, float s) {
#pragma unroll
    for (int p = 0; p < 16; ++p) {
        float lo = v[p].x, hi = v[p].y;
        v[p].x = fmaf(-s, hi, c * lo);
        v[p].y = fmaf(s, lo, c * hi);
    }
}

// ---------------------------------------------------------------------------
// Stage 1: build circuit unitary U (256x256 real orthogonal) by pushing the
// 256 basis columns through the R3-verified simulator. Store fp16 MFMA
// A-frags **mt-major** so stage-2 can phase over state rows (full K per phase):
//   uf[((mt*8 + ks)*64 + lf)*8 + j] = U[m][k],
//   m = 16*mt + (lf&15), k = 32*ks + (lf>>4)*8 + j.
// Dropped exactly (commute with observables on wires 6,7): w18..21, w24, w25.
// ---------------------------------------------------------------------------
__global__ __launch_bounds__(256) void qae_buildU(const float* __restrict__ w,
                                                  _Float16* __restrict__ uf) {
    __shared__ float4 lds4[2048];
    const int lane = threadIdx.x & 63;
    const int wid  = threadIdx.x >> 6;
    const int wave = blockIdx.x * 4 + wid;
    const int l3   = lane & 7;
    const int e    = lane >> 3;
    const int col  = wave * 8 + e;           // basis column 0..255
    float4* W = lds4 + wid * 512 + e * 64;

    float h = 0.f;
    if (lane < 20) h = 0.5f * w[lane < 18 ? lane : lane + 4];
    const float cv = __cosf(h), sv = __sinf(h);
#define RYP(B2, slot) ry_pk<B2>(v, rl(cv, slot), rl(sv, slot))
#define RYI(slot)     ry_intra(v, rl(cv, slot), rl(sv, slot))

    const int a0 = (l3 >> 2) & 1, a1 = (l3 >> 1) & 1, a2 = l3 & 1;
    const int aa = a0 & a1, dd = a0 ^ a1;
    const float fE = (aa ^ (dd & a2)) ? -1.f : 1.f;
    const float fO = ((aa ^ (dd & a2)) ^ dd) ? -1.f : 1.f;
    const float pB = (__popc(l3) & 1) ? -1.f : 1.f;
    const v2f mA0 = mk2(fE, fO), mA1 = mk2(fO, fE);
    const v2f mBp = mk2(pB, -pB);

    v2f v[16];
#pragma unroll
    for (int p = 0; p < 16; ++p) v[p] = mk2(0.f, 0.f);
    // basis vector e_col in layout B: amp a = (u:w0w1w2)*32 + l3*4 + (t:w6w7)
    if (((col >> 2) & 7) == l3) {
        const int p = 2 * (col >> 5) + ((col >> 1) & 1);
        if (col & 1) v[p].y = 1.f; else v[p].x = 1.f;
    }

    // B: layer-0 wires 0,1,2
    RYP(3, 0); RYP(2, 1); RYP(1, 2);
    // transpose B->A
#pragma unroll
    for (int g = 0; g < 8; ++g)
        W[g * 8 + (l3 ^ g)] = make_float4(v[2*g].x, v[2*g].y, v[2*g+1].x, v[2*g+1].y);
#pragma unroll
    for (int k = 0; k < 8; ++k) {
        float4 f = W[l3 * 8 + (k ^ l3)];
        v[2*k] = mk2(f.x, f.y); v[2*k+1] = mk2(f.z, f.w);
    }
    // A: L0 wires 3..7 ; CZ0 ; L1 wires 3..7
    RYP(3, 3); RYP(2, 4); RYP(1, 5); RYP(0, 6); RYI(7);
#pragma unroll
    for (int p = 0; p < 16; ++p) v[p] *= (__popc(p) & 1) ? mA1 : mA0;
    RYP(3, 11); RYP(2, 12); RYP(1, 13); RYP(0, 14); RYI(15);
    // transpose A->B
#pragma unroll
    for (int k = 0; k < 8; ++k)
        W[l3 * 8 + (k ^ l3)] = make_float4(v[2*k].x, v[2*k].y, v[2*k+1].x, v[2*k+1].y);
#pragma unroll
    for (int g = 0; g < 8; ++g) {
        float4 f = W[g * 8 + (l3 ^ g)];
        v[2*g] = mk2(f.x, f.y); v[2*g+1] = mk2(f.z, f.w);
    }
    // B: L1 wires 0,1,2 ; CZ1 ; L2 {0,1,6,7} ; CZ2
    RYP(3, 8); RYP(2, 9); RYP(1, 10);
#pragma unroll
    for (int p = 0; p < 16; ++p) {
        const int b0 = (p >> 3) & 1, b1 = (p >> 2) & 1;
        if (b0 & b1)      v[p] = -v[p];
        else if (b0 ^ b1) v[p] *= (__popc(p & 3) & 1) ? -mBp : mBp;
    }
    RYP(3, 16); RYP(2, 17); RYP(0, 18); RYI(19);
#pragma unroll
    for (int p = 0; p < 16; ++p) {
        const int b0 = (p >> 3) & 1, b1 = (p >> 2) & 1;
        if (b0 & b1)      v[p] = -v[p];
        else if (b0 ^ b1) v[p] *= (__popc(p & 3) & 1) ? -mBp : mBp;
    }
#undef RYP
#undef RYI

    // scatter-store fp16 A-fragments, mt-major (k = col for every amp)
    const int ks = col >> 5, j = col & 7, lfhi = ((col >> 3) & 3) << 4;
#pragma unroll
    for (int p = 0; p < 16; ++p) {
        const int mbase = ((p >> 1) << 5) | (l3 << 2) | ((p & 1) << 1);
        {   const int m = mbase, mt = m >> 4, lf = (m & 15) | lfhi;
            uf[(size_t)(((mt * 8 + ks) * 64 + lf) * 8 + j)] = (_Float16)v[p].x; }
        {   const int m = mbase | 1, mt = m >> 4, lf = (m & 15) | lfhi;
            uf[(size_t)(((mt * 8 + ks) * 64 + lf) * 8 + j)] = (_Float16)v[p].y; }
    }
}

// ---------------------------------------------------------------------------
// Stage 2: psi = U x for 16 batch rows per wave via mfma_f32_16x16x32_f16.
// Phases cover 4 m-tiles each with FULL K (8 MFMAs -> complete psi row-quad
// in-lane), then observables. C layout: col=lane&15=batch, row=(lane>>4)*4+reg
// = state -> lane's 4 acc regs are one (w6,w7) amplitude group.
// ---------------------------------------------------------------------------
__global__ __launch_bounds__(256) void qae_gemm(const float* __restrict__ x,
                                                const _Float16* __restrict__ uf,
                                                float* __restrict__ out, int batch) {
    __shared__ __align__(16) _Float16 Ut[16384];   // 32 KB: 4 m-tiles x all K
    const int lane  = threadIdx.x & 63;
    const int wid   = threadIdx.x >> 6;
    const int strip = blockIdx.x * 4 + wid;        // 16 batch rows per wave
    const int bl = lane & 15, bq = lane >> 4;
    const int b  = strip * 16 + bl;
    const bool act = (b < batch);

    // x fragments (B-operand: n = lane&15, k = bq*8 + j + 32*ks) + fp32 norm
    const float* xp = x + (size_t)b * DIM + bq * 8;
    f16x8 bf[8];
    float nrm = 0.f;
#pragma unroll
    for (int ks = 0; ks < 8; ++ks) {
        float4 f0 = make_float4(0.f, 0.f, 0.f, 0.f), f1 = f0;
        if (act) { f0 = *(const float4*)(xp + 32 * ks);
                   f1 = *(const float4*)(xp + 32 * ks + 4); }
        nrm += f0.x*f0.x + f0.y*f0.y + f0.z*f0.z + f0.w*f0.w
             + f1.x*f1.x + f1.y*f1.y + f1.z*f1.z + f1.w*f1.w;
        bf[ks][0] = (_Float16)f0.x; bf[ks][1] = (_Float16)f0.y;
        bf[ks][2] = (_Float16)f0.z; bf[ks][3] = (_Float16)f0.w;
        bf[ks][4] = (_Float16)f1.x; bf[ks][5] = (_Float16)f1.y;
        bf[ks][6] = (_Float16)f1.z; bf[ks][7] = (_Float16)f1.w;
    }

    float pX6 = 0, pX7 = 0, pXX = 0, pYY = 0, pZ6 = 0, pZ7 = 0, pZZ = 0;

#pragma unroll
    for (int ph = 0; ph < 4; ++ph) {               // m-tiles 4ph..4ph+3, full K
        __syncthreads();                           // retire previous phase reads
        const float4* src = (const float4*)uf + (size_t)ph * 2048 + threadIdx.x;
        float4* dst = (float4*)Ut;
#pragma unroll
        for (int i = 0; i < 8; ++i)                // 32 KB / 256 threads
            dst[i * 256 + threadIdx.x] = src[i * 256];
        __syncthreads();
#pragma unroll
        for (int mtl = 0; mtl < 4; ++mtl) {
            f32x4 acc = {0.f, 0.f, 0.f, 0.f};
#pragma unroll
            for (int ks = 0; ks < 8; ++ks) {       // FULL K before squaring
                f16x8 af = *(const f16x8*)(Ut + ((mtl * 8 + ks) * 64 + lane) * 8);
                acc = __builtin_amdgcn_mfma_f32_16x16x32_f16(af, bf[ks], acc, 0, 0, 0);
            }
            const float q0 = acc[0], q1 = acc[1], q2 = acc[2], q3 = acc[3];
            pX6 += q0 * q2 + q1 * q3;
            pX7 += q0 * q1 + q2 * q3;
            pXX += q0 * q3 + q1 * q2;
            pYY += q1 * q2 - q0 * q3;
            const float s0 = q0*q0, s1 = q1*q1, s2 = q2*q2, s3 = q3*q3;
            pZ6 += (s0 + s1) - (s2 + s3);
            pZ7 += (s0 - s1) + (s2 - s3);
            pZZ += (s0 - s1) - (s2 - s3);
        }
    }

    // sum the 4 lane-quads (same batch col, disjoint state rows)
#pragma unroll
    for (int m = 16; m <= 32; m <<= 1) {
        nrm += __shfl_xor(nrm, m);
        pX6 += __shfl_xor(pX6, m); pX7 += __shfl_xor(pX7, m);
        pXX += __shfl_xor(pXX, m); pYY += __shfl_xor(pYY, m);
        pZ6 += __shfl_xor(pZ6, m); pZ7 += __shfl_xor(pZ7, m);
        pZZ += __shfl_xor(pZZ, m);
    }

    if (act && bq == 0) {
        const float inv = 1.f / nrm;               // U orthogonal: norm from x
        float* o = out + (size_t)b * 9;
        o[0] = 2.f * pX6 * inv;  o[1] = 0.f;  o[2] = pZ6 * inv;
        o[3] = 2.f * pX7 * inv;  o[4] = 0.f;  o[5] = pZ7 * inv;
        o[6] = 2.f * pXX * inv;  o[7] = 2.f * pYY * inv;  o[8] = pZZ * inv;
    }
}

extern "C" void kernel_launch(void* const* d_in, const int* in_sizes, int n_in,
                              void* d_out, int out_size, void* d_ws, size_t ws_size,
                              hipStream_t stream) {
    const float* x = (const float*)d_in[0];
    const float* w = (const float*)d_in[1];
    float* out = (float*)d_out;
    _Float16* uf = (_Float16*)d_ws;                // 128 KB of fragments
    const int batch = in_sizes[0] / DIM;

    qae_buildU<<<8, 256, 0, stream>>>(w, uf);

    const int strips = (batch + 15) / 16;
    qae_gemm<<<(strips + 3) / 4, 256, 0, stream>>>(x, uf, out, batch);
}

// Round 7
// 85.599 us; speedup vs baseline: 1.0822x; 1.0822x over previous
//
#include <hip/hip_runtime.h>
#include <math.h>

#define DIM 256
typedef float v2f  __attribute__((ext_vector_type(2)));
typedef _Float16 f16x8 __attribute__((ext_vector_type(8)));
typedef _Float16 f16x4 __attribute__((ext_vector_type(4)));
typedef float f32x4 __attribute__((ext_vector_type(4)));

__device__ __forceinline__ v2f mk2(float a, float b) { v2f r; r.x = a; r.y = b; return r; }
__device__ __forceinline__ float rl(float v, int l) {
    return __uint_as_float(__builtin_amdgcn_readlane(__float_as_uint(v), l));
}

// RY on v2f-index bit B2 (amp bit B2+1) of a 16-entry array.
template<int B2>
__device__ __forceinline__ void ry_pk(v2f* v, float c, float s) {
#pragma unroll
    for (int p = 0; p < 16; ++p)
        if (!(p & (1 << B2))) {
            const int q = p | (1 << B2);
            v2f lo = v[p], hi = v[q];
            v[p] = c * lo - s * hi;
            v[q] = s * lo + c * hi;
        }
}
__device__ __forceinline__ void ry_intra(v2f* v, float c, float s) {
#pragma unroll
    for (int p = 0; p < 16; ++p) {
        float lo = v[p].x, hi = v[p].y;
        v[p].x = fmaf(-s, hi, c * lo);
        v[p].y = fmaf(s, lo, c * hi);
    }
}

// ---------------------------------------------------------------------------
// Stage 1: build circuit unitary U (256x256 real orthogonal) by pushing the
// 256 basis columns through the R3-verified simulator. New: results are
// transposed in wave-private LDS and stored as fp16 MFMA A-frags with
// COALESCED 16 B stores (j=e packed in-lane):
//   uf[((mt*8 + ks)*64 + lf)*8 + j] = U[m][k],
//   m = 16mt + (lf&15), k = 32ks + (lf>>4)*8 + j;  here k = col = wave*8 + e.
// Dropped exactly (commute with observables on wires 6,7): w18..21, w24, w25.
// ---------------------------------------------------------------------------
__global__ __launch_bounds__(256) void qae_buildU(const float* __restrict__ w,
                                                  _Float16* __restrict__ uf) {
    __shared__ float4 lds4[2048];
    const int lane = threadIdx.x & 63;
    const int wid  = threadIdx.x >> 6;
    const int wave = blockIdx.x * 4 + wid;
    const int l3   = lane & 7;
    const int e    = lane >> 3;
    const int col  = wave * 8 + e;           // basis column 0..255
    float4* W = lds4 + wid * 512 + e * 64;

    float h = 0.f;
    if (lane < 20) h = 0.5f * w[lane < 18 ? lane : lane + 4];
    const float cv = __cosf(h), sv = __sinf(h);
#define RYP(B2, slot) ry_pk<B2>(v, rl(cv, slot), rl(sv, slot))
#define RYI(slot)     ry_intra(v, rl(cv, slot), rl(sv, slot))

    const int a0 = (l3 >> 2) & 1, a1 = (l3 >> 1) & 1, a2 = l3 & 1;
    const int aa = a0 & a1, dd = a0 ^ a1;
    const float fE = (aa ^ (dd & a2)) ? -1.f : 1.f;
    const float fO = ((aa ^ (dd & a2)) ^ dd) ? -1.f : 1.f;
    const float pB = (__popc(l3) & 1) ? -1.f : 1.f;
    const v2f mA0 = mk2(fE, fO), mA1 = mk2(fO, fE);
    const v2f mBp = mk2(pB, -pB);

    v2f v[16];
#pragma unroll
    for (int p = 0; p < 16; ++p) v[p] = mk2(0.f, 0.f);
    // basis vector e_col in layout B: amp a = (u:w0w1w2)*32 + l3*4 + (t:w6w7)
    if (((col >> 2) & 7) == l3) {
        const int p = 2 * (col >> 5) + ((col >> 1) & 1);
        if (col & 1) v[p].y = 1.f; else v[p].x = 1.f;
    }

    // B: layer-0 wires 0,1,2
    RYP(3, 0); RYP(2, 1); RYP(1, 2);
    // transpose B->A
#pragma unroll
    for (int g = 0; g < 8; ++g)
        W[g * 8 + (l3 ^ g)] = make_float4(v[2*g].x, v[2*g].y, v[2*g+1].x, v[2*g+1].y);
#pragma unroll
    for (int k = 0; k < 8; ++k) {
        float4 f = W[l3 * 8 + (k ^ l3)];
        v[2*k] = mk2(f.x, f.y); v[2*k+1] = mk2(f.z, f.w);
    }
    // A: L0 wires 3..7 ; CZ0 ; L1 wires 3..7
    RYP(3, 3); RYP(2, 4); RYP(1, 5); RYP(0, 6); RYI(7);
#pragma unroll
    for (int p = 0; p < 16; ++p) v[p] *= (__popc(p) & 1) ? mA1 : mA0;
    RYP(3, 11); RYP(2, 12); RYP(1, 13); RYP(0, 14); RYI(15);
    // transpose A->B
#pragma unroll
    for (int k = 0; k < 8; ++k)
        W[l3 * 8 + (k ^ l3)] = make_float4(v[2*k].x, v[2*k].y, v[2*k+1].x, v[2*k+1].y);
#pragma unroll
    for (int g = 0; g < 8; ++g) {
        float4 f = W[g * 8 + (l3 ^ g)];
        v[2*g] = mk2(f.x, f.y); v[2*g+1] = mk2(f.z, f.w);
    }
    // B: L1 wires 0,1,2 ; CZ1 ; L2 {0,1,6,7} ; CZ2
    RYP(3, 8); RYP(2, 9); RYP(1, 10);
#pragma unroll
    for (int p = 0; p < 16; ++p) {
        const int b0 = (p >> 3) & 1, b1 = (p >> 2) & 1;
        if (b0 & b1)      v[p] = -v[p];
        else if (b0 ^ b1) v[p] *= (__popc(p & 3) & 1) ? -mBp : mBp;
    }
    RYP(3, 16); RYP(2, 17); RYP(0, 18); RYI(19);
#pragma unroll
    for (int p = 0; p < 16; ++p) {
        const int b0 = (p >> 3) & 1, b1 = (p >> 2) & 1;
        if (b0 & b1)      v[p] = -v[p];
        else if (b0 ^ b1) v[p] *= (__popc(p & 3) & 1) ? -mBp : mBp;
    }
#undef RYP
#undef RYI

    // In-wave transpose: T[m][e] fp16 (4 KB, aliases this wave's circuit slice
    // - circuit DS ops retired in program order, same wave -> no barrier).
    _Float16* T = (_Float16*)(lds4 + wid * 512);
#pragma unroll
    for (int p = 0; p < 16; ++p) {
        const int m0 = ((p >> 1) << 5) | (l3 << 2) | ((p & 1) << 1);
        T[m0 * 8 + e]       = (_Float16)v[p].x;
        T[(m0 + 1) * 8 + e] = (_Float16)v[p].y;
    }
    // Coalesced frag stores: lane packs j=0..7 (= e = col&7) for 4 m's.
    const int ksv = wave >> 2, lfh = (wave & 3) << 4;
#pragma unroll
    for (int i = 0; i < 4; ++i) {
        const int m = lane * 4 + i;
        const int mt = m >> 4, lf = (m & 15) | lfh;
        f16x8 t = *(const f16x8*)(T + m * 8);
        *(f16x8*)(uf + (size_t)(((mt * 8 + ksv) * 64 + lf) * 8)) = t;
    }
}

// ---------------------------------------------------------------------------
// Stage 2: psi = U x, 16 batch rows per wave via mfma_f32_16x16x32_f16.
// x loaded one-full-row-per-instruction (perfectly coalesced, zero overfetch),
// fp16-converted, transposed through a per-wave 8 KB LDS slice into B-frags.
// U staged in 4 x 32 KB phases (4 m-tiles, full K each -> complete psi quad
// in-lane before squaring). C layout: col=lane&15=batch, row=(lane>>4)*4+reg.
// ---------------------------------------------------------------------------
__global__ __launch_bounds__(256, 2) void qae_gemm(const float* __restrict__ x,
                                                   const _Float16* __restrict__ uf,
                                                   float* __restrict__ out, int batch) {
    __shared__ __align__(16) _Float16 Xs[4][4096];   // 32 KB: 4 waves x 16 rows x 256
    __shared__ __align__(16) _Float16 Ut[16384];     // 32 KB: 4 m-tiles x full K
    const int lane  = threadIdx.x & 63;
    const int wid   = threadIdx.x >> 6;
    const int strip = blockIdx.x * 4 + wid;          // 16 batch rows per wave
    const int bl = lane & 15, bq = lane >> 4;
    const int b  = strip * 16 + bl;

    // ---- coalesced x load -> fp16 -> LDS (row r: 64 lanes x 16 B = the row) ----
    _Float16* Xw = Xs[wid];
#pragma unroll
    for (int r = 0; r < 16; ++r) {
        int gr = strip * 16 + r; if (gr >= batch) gr = batch - 1;
        const float4 f = *(const float4*)(x + (size_t)gr * DIM + lane * 4);
        f16x4 hh;
        hh[0] = (_Float16)f.x; hh[1] = (_Float16)f.y;
        hh[2] = (_Float16)f.z; hh[3] = (_Float16)f.w;
        *(f16x4*)(Xw + r * 256 + lane * 4) = hh;     // ds_write_b64
    }
    // ---- B-frags: lane (bl,bq) reads row bl, k = 32ks + 8bq + j  (same wave) ----
    f16x8 bf[8];
    float nrm = 0.f;                                 // norm of fp16(x) in fp32
#pragma unroll
    for (int ks = 0; ks < 8; ++ks) {
        bf[ks] = *(const f16x8*)(Xw + bl * 256 + ks * 32 + bq * 8);
#pragma unroll
        for (int j = 0; j < 8; ++j) { float t = (float)bf[ks][j]; nrm = fmaf(t, t, nrm); }
    }

    float pX6 = 0, pX7 = 0, pXX = 0, pYY = 0, pZ6 = 0, pZ7 = 0, pZZ = 0;

#pragma unroll
    for (int ph = 0; ph < 4; ++ph) {                 // m-tiles 4ph..4ph+3, full K
        __syncthreads();                             // retire previous phase reads
        const float4* src = (const float4*)uf + (size_t)ph * 2048 + threadIdx.x;
        float4* dst = (float4*)Ut;
#pragma unroll
        for (int i = 0; i < 8; ++i)                  // 32 KB / 256 threads
            dst[i * 256 + threadIdx.x] = src[i * 256];
        __syncthreads();
#pragma unroll
        for (int mtl = 0; mtl < 4; ++mtl) {
            f32x4 acc = {0.f, 0.f, 0.f, 0.f};
#pragma unroll
            for (int ks = 0; ks < 8; ++ks) {         // FULL K before squaring
                f16x8 af = *(const f16x8*)(Ut + ((mtl * 8 + ks) * 64 + lane) * 8);
                acc = __builtin_amdgcn_mfma_f32_16x16x32_f16(af, bf[ks], acc, 0, 0, 0);
            }
            const float q0 = acc[0], q1 = acc[1], q2 = acc[2], q3 = acc[3];
            pX6 += q0 * q2 + q1 * q3;
            pX7 += q0 * q1 + q2 * q3;
            pXX += q0 * q3 + q1 * q2;
            pYY += q1 * q2 - q0 * q3;
            const float s0 = q0*q0, s1 = q1*q1, s2 = q2*q2, s3 = q3*q3;
            pZ6 += (s0 + s1) - (s2 + s3);
            pZ7 += (s0 - s1) + (s2 - s3);
            pZZ += (s0 - s1) - (s2 - s3);
        }
    }

    // sum the 4 lane-quads (same batch col, disjoint state rows)
#pragma unroll
    for (int m = 16; m <= 32; m <<= 1) {
        nrm += __shfl_xor(nrm, m);
        pX6 += __shfl_xor(pX6, m); pX7 += __shfl_xor(pX7, m);
        pXX += __shfl_xor(pXX, m); pYY += __shfl_xor(pYY, m);
        pZ6 += __shfl_xor(pZ6, m); pZ7 += __shfl_xor(pZ7, m);
        pZZ += __shfl_xor(pZZ, m);
    }

    if (b < batch && bq == 0) {
        const float inv = 1.f / nrm;                 // U orthogonal: norm from x
        float* o = out + (size_t)b * 9;
        o[0] = 2.f * pX6 * inv;  o[1] = 0.f;  o[2] = pZ6 * inv;
        o[3] = 2.f * pX7 * inv;  o[4] = 0.f;  o[5] = pZ7 * inv;
        o[6] = 2.f * pXX * inv;  o[7] = 2.f * pYY * inv;  o[8] = pZZ * inv;
    }
}

extern "C" void kernel_launch(void* const* d_in, const int* in_sizes, int n_in,
                              void* d_out, int out_size, void* d_ws, size_t ws_size,
                              hipStream_t stream) {
    const float* x = (const float*)d_in[0];
    const float* w = (const float*)d_in[1];
    float* out = (float*)d_out;
    _Float16* uf = (_Float16*)d_ws;                  // 128 KB of fragments
    const int batch = in_sizes[0] / DIM;

    qae_buildU<<<8, 256, 0, stream>>>(w, uf);

    const int strips = (batch + 15) / 16;
    qae_gemm<<<(strips + 3) / 4, 256, 0, stream>>>(x, uf, out, batch);
}